// Round 2
// baseline (538.924 us; speedup 1.0000x reference)
//
#include <hip/hip_runtime.h>

typedef unsigned short u16;
typedef __attribute__((ext_vector_type(8))) short bf16x8;
typedef __attribute__((ext_vector_type(4))) float f32x4;

__device__ __forceinline__ float bf2f(u16 h) {
    return __uint_as_float(((unsigned int)h) << 16);
}
__device__ __forceinline__ u16 f2bf(float f) {
    unsigned int u = __float_as_uint(f);
    u += 0x7FFFu + ((u >> 16) & 1u);   // RNE
    return (u16)(u >> 16);
}

// ---------------------------------------------------------------------------
// Dtype detection: even-index ushorts of an fp32 N(0,1) buffer are random
// mantissa halves (exponent field uniform); of a bf16 buffer they're sane
// exponents in [116,132] (|x| in [2^-11, 2^5]). 128-sample vote.
// flag = 1 -> inputs are bf16; flag = 0 -> inputs are fp32.
// ---------------------------------------------------------------------------
__global__ void detect_dtype(const u16* __restrict__ x, int* __restrict__ flag) {
    __shared__ int cnt;
    if (threadIdx.x == 0) cnt = 0;
    __syncthreads();
    unsigned e = (x[2 * threadIdx.x] >> 7) & 0xFF;
    if (e >= 116 && e <= 132) atomicAdd(&cnt, 1);
    __syncthreads();
    if (threadIdx.x == 0) *flag = (cnt >= 96) ? 1 : 0;
}

// ---------------------------------------------------------------------------
// Elementwise convert to bf16 (or bit-copy if already bf16). n4 = n/4.
// ---------------------------------------------------------------------------
__global__ __launch_bounds__(256) void convert_in(
    const void* __restrict__ in, u16* __restrict__ out, long n4,
    const int* __restrict__ flag)
{
    long i = (long)blockIdx.x * blockDim.x + threadIdx.x;
    if (i >= n4) return;
    if (*flag) {
        ((ushort4*)out)[i] = ((const ushort4*)in)[i];
    } else {
        float4 v = ((const float4*)in)[i];
        ushort4 r;
        r.x = f2bf(v.x); r.y = f2bf(v.y); r.z = f2bf(v.z); r.w = f2bf(v.w);
        ((ushort4*)out)[i] = r;
    }
}

// ---------------------------------------------------------------------------
// Transpose [R x Cc] -> [Cc x R] with dtype convert fused.
// ---------------------------------------------------------------------------
__global__ __launch_bounds__(256) void transpose_conv(
    const void* __restrict__ in, u16* __restrict__ out, int R, int Cc,
    const int* __restrict__ flag)
{
    __shared__ u16 tile[32][33];
    int tx = threadIdx.x & 31, ty = threadIdx.x >> 5;   // ty 0..7
    int c0 = blockIdx.x * 32, r0 = blockIdx.y * 32;
    bool isbf = (*flag != 0);
#pragma unroll
    for (int g = 0; g < 4; ++g) {
        size_t idx = (size_t)(r0 + ty + g * 8) * Cc + c0 + tx;
        tile[ty + g * 8][tx] = isbf ? ((const u16*)in)[idx]
                                    : f2bf(((const float*)in)[idx]);
    }
    __syncthreads();
#pragma unroll
    for (int g = 0; g < 4; ++g)
        out[(size_t)(c0 + ty + g * 8) * R + r0 + tx] = tile[tx][ty + g * 8];
}

// ---------------------------------------------------------------------------
// C[M,N] = A[M,K] @ W + bias, Bt = W^T as [N,K] bf16. A is bf16.
// 128x128 tile, BK=64, 4 waves x (64x64), mfma_f32_16x16x32_bf16.
// bias read per *flag dtype. If final_out && !*flag, store fp32, else bf16.
// ---------------------------------------------------------------------------
__global__ __launch_bounds__(256, 2) void gemm_bias(
    const u16* __restrict__ A, const u16* __restrict__ Bt,
    const void* __restrict__ bias, void* __restrict__ C,
    int M, int N, int K, int final_out, const int* __restrict__ flag)
{
    __shared__ u16 As[128][72];
    __shared__ u16 Bs[128][72];

    const int tid  = threadIdx.x;
    const int m0   = blockIdx.y * 128, n0 = blockIdx.x * 128;
    const int lane = tid & 63, wid = tid >> 6;
    const int wm   = (wid >> 1) * 64, wn = (wid & 1) * 64;
    const int m16  = lane & 15, quad = lane >> 4;
    const int isbf = *flag;

    const int lrow   = tid >> 3;        // 0..31
    const int lchunk = (tid & 7) * 8;   // 16B chunks

    f32x4 acc[4][4];
#pragma unroll
    for (int i = 0; i < 4; ++i)
#pragma unroll
        for (int j = 0; j < 4; ++j)
            acc[i][j] = (f32x4){0.f, 0.f, 0.f, 0.f};

    for (int k0 = 0; k0 < K; k0 += 64) {
#pragma unroll
        for (int g = 0; g < 4; ++g) {
            int r = lrow + g * 32;
            *(int4*)&As[r][lchunk] =
                *(const int4*)&A[(size_t)(m0 + r) * K + k0 + lchunk];
            *(int4*)&Bs[r][lchunk] =
                *(const int4*)&Bt[(size_t)(n0 + r) * K + k0 + lchunk];
        }
        __syncthreads();
#pragma unroll
        for (int ks = 0; ks < 64; ks += 32) {
            bf16x8 a[4], b[4];
#pragma unroll
            for (int i = 0; i < 4; ++i)
                a[i] = *(bf16x8*)&As[wm + i * 16 + m16][ks + quad * 8];
#pragma unroll
            for (int j = 0; j < 4; ++j)
                b[j] = *(bf16x8*)&Bs[wn + j * 16 + m16][ks + quad * 8];
#pragma unroll
            for (int i = 0; i < 4; ++i)
#pragma unroll
                for (int j = 0; j < 4; ++j)
                    acc[i][j] = __builtin_amdgcn_mfma_f32_16x16x32_bf16(
                        a[i], b[j], acc[i][j], 0, 0, 0);
        }
        __syncthreads();
    }

    const bool out_f32 = final_out && !isbf;
#pragma unroll
    for (int i = 0; i < 4; ++i) {
        int grow = m0 + wm + i * 16 + quad * 4;
#pragma unroll
        for (int j = 0; j < 4; ++j) {
            int gcol = n0 + wn + j * 16 + m16;
            float bv = isbf ? bf2f(((const u16*)bias)[gcol])
                            : ((const float*)bias)[gcol];
#pragma unroll
            for (int r = 0; r < 4; ++r) {
                float val = acc[i][j][r] + bv;
                size_t idx = (size_t)(grow + r) * N + gcol;
                if (out_f32) ((float*)C)[idx] = val;
                else         ((u16*)C)[idx]   = f2bf(val);
            }
        }
    }
}

// ---------------------------------------------------------------------------
// Flash attention (causal). One block per (b, h, 128-row q tile), 4 waves.
// All buffers bf16 (internal workspace).
// ---------------------------------------------------------------------------
__global__ __launch_bounds__(256, 1) void attn_flash(
    const u16* __restrict__ Q, const u16* __restrict__ Kb,
    const u16* __restrict__ Vb, u16* __restrict__ O,
    int T, int C)
{
    __shared__ u16 Qs[128][72];
    __shared__ u16 Ks[128][72];
    __shared__ u16 Vts[64][136];
    __shared__ u16 Ps[128][136];

    const int tid  = threadIdx.x;
    const int lane = tid & 63, wid = tid >> 6;
    const int m16  = lane & 15, quad = lane >> 4;
    const int qt = blockIdx.x, h = blockIdx.y, b = blockIdx.z;
    const float scale = 0.125f;   // 1/sqrt(64)
    const float NEG = -3.0e4f;

    const size_t headoff = ((size_t)b * T) * C + h * 64;

    const int lrow   = tid >> 3;
    const int lchunk = (tid & 7) * 8;

#pragma unroll
    for (int g = 0; g < 4; ++g) {
        int r = lrow + g * 32;
        *(int4*)&Qs[r][lchunk] =
            *(const int4*)&Q[headoff + (size_t)(qt * 128 + r) * C + lchunk];
    }

    float m_run[2][4], l_run[2][4];
    f32x4 o_acc[2][4];
#pragma unroll
    for (int i = 0; i < 2; ++i)
#pragma unroll
        for (int r = 0; r < 4; ++r) { m_run[i][r] = NEG; l_run[i][r] = 0.f; }
#pragma unroll
    for (int i = 0; i < 2; ++i)
#pragma unroll
        for (int n = 0; n < 4; ++n) o_acc[i][n] = (f32x4){0.f, 0.f, 0.f, 0.f};

    for (int st = 0; st <= qt; ++st) {
        __syncthreads();
#pragma unroll
        for (int g = 0; g < 4; ++g) {
            int r = lrow + g * 32;
            *(int4*)&Ks[r][lchunk] =
                *(const int4*)&Kb[headoff + (size_t)(st * 128 + r) * C + lchunk];
        }
        {
            int s = tid >> 1, cb = (tid & 1) * 32;
            const int4* vp =
                (const int4*)&Vb[headoff + (size_t)(st * 128 + s) * C + cb];
#pragma unroll
            for (int q4 = 0; q4 < 4; ++q4) {
                union { int4 v; u16 u[8]; } tmp;
                tmp.v = vp[q4];
#pragma unroll
                for (int e = 0; e < 8; ++e) Vts[cb + q4 * 8 + e][s] = tmp.u[e];
            }
        }
        __syncthreads();

        f32x4 sacc[2][8];
#pragma unroll
        for (int i = 0; i < 2; ++i)
#pragma unroll
            for (int j = 0; j < 8; ++j) sacc[i][j] = (f32x4){0.f, 0.f, 0.f, 0.f};
#pragma unroll
        for (int ks = 0; ks < 64; ks += 32) {
            bf16x8 aq[2], bk[8];
#pragma unroll
            for (int i = 0; i < 2; ++i)
                aq[i] = *(bf16x8*)&Qs[wid * 32 + i * 16 + m16][ks + quad * 8];
#pragma unroll
            for (int j = 0; j < 8; ++j)
                bk[j] = *(bf16x8*)&Ks[j * 16 + m16][ks + quad * 8];
#pragma unroll
            for (int i = 0; i < 2; ++i)
#pragma unroll
                for (int j = 0; j < 8; ++j)
                    sacc[i][j] = __builtin_amdgcn_mfma_f32_16x16x32_bf16(
                        aq[i], bk[j], sacc[i][j], 0, 0, 0);
        }

#pragma unroll
        for (int i = 0; i < 2; ++i) {
            int qrow_base = qt * 128 + wid * 32 + i * 16 + quad * 4;
#pragma unroll
            for (int j = 0; j < 8; ++j) {
                int sg = st * 128 + j * 16 + m16;
#pragma unroll
                for (int r = 0; r < 4; ++r) {
                    float v = sacc[i][j][r] * scale;
                    if (sg > qrow_base + r) v = NEG;
                    sacc[i][j][r] = v;
                }
            }
            float pm[4];
#pragma unroll
            for (int r = 0; r < 4; ++r) {
                pm[r] = NEG;
#pragma unroll
                for (int j = 0; j < 8; ++j) pm[r] = fmaxf(pm[r], sacc[i][j][r]);
            }
#pragma unroll
            for (int off = 1; off < 16; off <<= 1)
#pragma unroll
                for (int r = 0; r < 4; ++r)
                    pm[r] = fmaxf(pm[r], __shfl_xor(pm[r], off));

            float alpha[4], mn[4], rs[4];
#pragma unroll
            for (int r = 0; r < 4; ++r) {
                mn[r] = fmaxf(m_run[i][r], pm[r]);
                alpha[r] = __expf(m_run[i][r] - mn[r]);
                m_run[i][r] = mn[r];
                rs[r] = 0.f;
            }
#pragma unroll
            for (int j = 0; j < 8; ++j) {
#pragma unroll
                for (int r = 0; r < 4; ++r) {
                    float p = __expf(sacc[i][j][r] - mn[r]);
                    rs[r] += p;
                    Ps[wid * 32 + i * 16 + quad * 4 + r][j * 16 + m16] = f2bf(p);
                }
            }
#pragma unroll
            for (int off = 1; off < 16; off <<= 1)
#pragma unroll
                for (int r = 0; r < 4; ++r) rs[r] += __shfl_xor(rs[r], off);
#pragma unroll
            for (int r = 0; r < 4; ++r)
                l_run[i][r] = l_run[i][r] * alpha[r] + rs[r];
#pragma unroll
            for (int n = 0; n < 4; ++n)
#pragma unroll
                for (int r = 0; r < 4; ++r) o_acc[i][n][r] *= alpha[r];
        }
        __syncthreads();

#pragma unroll
        for (int k4 = 0; k4 < 4; ++k4) {
            bf16x8 ap[2], bv[4];
#pragma unroll
            for (int i = 0; i < 2; ++i)
                ap[i] = *(bf16x8*)&Ps[wid * 32 + i * 16 + m16][k4 * 32 + quad * 8];
#pragma unroll
            for (int n = 0; n < 4; ++n)
                bv[n] = *(bf16x8*)&Vts[n * 16 + m16][k4 * 32 + quad * 8];
#pragma unroll
            for (int i = 0; i < 2; ++i)
#pragma unroll
                for (int n = 0; n < 4; ++n)
                    o_acc[i][n] = __builtin_amdgcn_mfma_f32_16x16x32_bf16(
                        ap[i], bv[n], o_acc[i][n], 0, 0, 0);
        }
    }

#pragma unroll
    for (int i = 0; i < 2; ++i) {
#pragma unroll
        for (int n = 0; n < 4; ++n) {
#pragma unroll
            for (int r = 0; r < 4; ++r) {
                int tq = qt * 128 + wid * 32 + i * 16 + quad * 4 + r;
                O[((size_t)b * T + tq) * C + h * 64 + n * 16 + m16] =
                    f2bf(o_acc[i][n][r] / l_run[i][r]);
            }
        }
    }
}

// ---------------------------------------------------------------------------
extern "C" void kernel_launch(void* const* d_in, const int* in_sizes, int n_in,
                              void* d_out, int out_size, void* d_ws, size_t ws_size,
                              hipStream_t stream)
{
    const void* x  = d_in[0];
    const void* Wq = d_in[1];
    const void* bq = d_in[2];
    const void* Wk = d_in[3];
    const void* bk = d_in[4];
    const void* Wv = d_in[5];
    const void* bv = d_in[6];
    const void* Wp = d_in[7];
    const void* bp = d_in[8];

    const int Bb = 4, T = 2048, C = 1024, H = 16;
    const int M = Bb * T, N = C, K = C;

    u16* wsp = (u16*)d_ws;
    const size_t WSZ = (size_t)C * C;   // 1 Mi elems
    const size_t MSZ = (size_t)M * C;   // 8 Mi elems
    u16* WtQ = wsp;
    u16* WtK = wsp + WSZ;
    u16* WtV = wsp + 2 * WSZ;
    u16* WtP = wsp + 3 * WSZ;
    u16* xb  = wsp + 4 * WSZ;
    u16* Qb  = xb + MSZ;
    u16* Kbf = Qb + MSZ;
    u16* Vbf = Kbf + MSZ;
    u16* Ab  = Vbf + MSZ;
    int* flag = (int*)(Ab + MSZ);

    detect_dtype<<<1, 128, 0, stream>>>((const u16*)x, flag);

    convert_in<<<(int)(MSZ / 4 / 256), 256, 0, stream>>>(x, xb, MSZ / 4, flag);

    dim3 tb(256), tg(C / 32, C / 32);
    transpose_conv<<<tg, tb, 0, stream>>>(Wq, WtQ, C, C, flag);
    transpose_conv<<<tg, tb, 0, stream>>>(Wk, WtK, C, C, flag);
    transpose_conv<<<tg, tb, 0, stream>>>(Wv, WtV, C, C, flag);
    transpose_conv<<<tg, tb, 0, stream>>>(Wp, WtP, C, C, flag);

    dim3 gg(N / 128, M / 128), gb(256);
    gemm_bias<<<gg, gb, 0, stream>>>(xb, WtQ, bq, Qb,  M, N, K, 0, flag);
    gemm_bias<<<gg, gb, 0, stream>>>(xb, WtK, bk, Kbf, M, N, K, 0, flag);
    gemm_bias<<<gg, gb, 0, stream>>>(xb, WtV, bv, Vbf, M, N, K, 0, flag);

    dim3 ag(T / 128, H, Bb), ab(256);
    attn_flash<<<ag, ab, 0, stream>>>(Qb, Kbf, Vbf, Ab, T, C);

    gemm_bias<<<gg, gb, 0, stream>>>(Ab, WtP, bp, d_out, M, N, K, 1, flag);
}

// Round 3
// 533.639 us; speedup vs baseline: 1.0099x; 1.0099x over previous
//
#include <hip/hip_runtime.h>

typedef unsigned short u16;
typedef __attribute__((ext_vector_type(8))) short bf16x8;
typedef __attribute__((ext_vector_type(4))) float f32x4;

__device__ __forceinline__ float bf2f(u16 h) {
    return __uint_as_float(((unsigned int)h) << 16);
}
__device__ __forceinline__ u16 f2bf(float f) {
    unsigned int u = __float_as_uint(f);
    u += 0x7FFFu + ((u >> 16) & 1u);   // RNE
    return (u16)(u >> 16);
}

// async global->LDS, 16 B per lane. LDS dest = wave-uniform base + lane*16.
__device__ __forceinline__ void gl2lds16(const u16* g, u16* l) {
    __builtin_amdgcn_global_load_lds(
        (const __attribute__((address_space(1))) unsigned int*)g,
        (__attribute__((address_space(3))) unsigned int*)l,
        16, 0, 0);
}

// ---------------------------------------------------------------------------
// Dtype detection (fp32 vs bf16 input buffers). flag=1 -> bf16.
// ---------------------------------------------------------------------------
__global__ void detect_dtype(const u16* __restrict__ x, int* __restrict__ flag) {
    __shared__ int cnt;
    if (threadIdx.x == 0) cnt = 0;
    __syncthreads();
    unsigned e = (x[2 * threadIdx.x] >> 7) & 0xFF;
    if (e >= 116 && e <= 132) atomicAdd(&cnt, 1);
    __syncthreads();
    if (threadIdx.x == 0) *flag = (cnt >= 96) ? 1 : 0;
}

// ---------------------------------------------------------------------------
// Elementwise convert to bf16 (or bit-copy). n4 = n/4.
// ---------------------------------------------------------------------------
__global__ __launch_bounds__(256) void convert_in(
    const void* __restrict__ in, u16* __restrict__ out, long n4,
    const int* __restrict__ flag)
{
    long i = (long)blockIdx.x * blockDim.x + threadIdx.x;
    if (i >= n4) return;
    if (*flag) {
        ((ushort4*)out)[i] = ((const ushort4*)in)[i];
    } else {
        float4 v = ((const float4*)in)[i];
        ushort4 r;
        r.x = f2bf(v.x); r.y = f2bf(v.y); r.z = f2bf(v.z); r.w = f2bf(v.w);
        ((ushort4*)out)[i] = r;
    }
}

// ---------------------------------------------------------------------------
// Transpose [R x Cc] -> [Cc x R] with dtype convert fused (weights).
// ---------------------------------------------------------------------------
__global__ __launch_bounds__(256) void transpose_conv(
    const void* __restrict__ in, u16* __restrict__ out, int R, int Cc,
    const int* __restrict__ flag)
{
    __shared__ u16 tile[32][33];
    int tx = threadIdx.x & 31, ty = threadIdx.x >> 5;
    int c0 = blockIdx.x * 32, r0 = blockIdx.y * 32;
    bool isbf = (*flag != 0);
#pragma unroll
    for (int g = 0; g < 4; ++g) {
        size_t idx = (size_t)(r0 + ty + g * 8) * Cc + c0 + tx;
        tile[ty + g * 8][tx] = isbf ? ((const u16*)in)[idx]
                                    : f2bf(((const float*)in)[idx]);
    }
    __syncthreads();
#pragma unroll
    for (int g = 0; g < 4; ++g)
        out[(size_t)(c0 + ty + g * 8) * R + r0 + tx] = tile[tx][ty + g * 8];
}

// ---------------------------------------------------------------------------
// V[b][s][h*64+d] -> Vt[(b*H+h)*64+d][s]   (bf16). Grid: (T/32, 2, B*H).
// ---------------------------------------------------------------------------
__global__ __launch_bounds__(256) void transpose_v(
    const u16* __restrict__ V, u16* __restrict__ Vt, int T, int C)
{
    __shared__ u16 tile[32][33];
    int tx = threadIdx.x & 31, ty = threadIdx.x >> 5;
    int s0 = blockIdx.x * 32, d0 = blockIdx.y * 32;
    int bh = blockIdx.z;              // b*16+h
    int b = bh >> 4, h = bh & 15;
#pragma unroll
    for (int g = 0; g < 4; ++g)
        tile[ty + g * 8][tx] =
            V[((size_t)b * T + s0 + ty + g * 8) * C + h * 64 + d0 + tx];
    __syncthreads();
#pragma unroll
    for (int g = 0; g < 4; ++g)
        Vt[((size_t)bh * 64 + d0 + ty + g * 8) * T + s0 + tx] =
            tile[tx][ty + g * 8];
}

// ---------------------------------------------------------------------------
// C[M,N] = A[M,K] @ W + bias, Bt = W^T [N,K] bf16. m97-style:
// unpadded LDS + global_load_lds width-16 staging. 128x128 tile, BK=64.
// ---------------------------------------------------------------------------
__global__ __launch_bounds__(256, 2) void gemm_bias(
    const u16* __restrict__ A, const u16* __restrict__ Bt,
    const void* __restrict__ bias, void* __restrict__ C,
    int M, int N, int K, int final_out, const int* __restrict__ flag)
{
    __shared__ __align__(16) u16 As[128 * 64];
    __shared__ __align__(16) u16 Bs[128 * 64];

    const int tid  = threadIdx.x;
    const int m0   = blockIdx.y * 128, n0 = blockIdx.x * 128;
    const int lane = tid & 63, wid = tid >> 6;
    const int wm   = (wid >> 1) * 64, wn = (wid & 1) * 64;
    const int m16  = lane & 15, quad = lane >> 4;
    const int isbf = *flag;

    const int srow   = wid * 8 + (lane >> 3);   // 0..31 per g-round
    const int schunk = (lane & 7) * 8;          // 16B chunk within 64-elem row

    f32x4 acc[4][4];
#pragma unroll
    for (int i = 0; i < 4; ++i)
#pragma unroll
        for (int j = 0; j < 4; ++j)
            acc[i][j] = (f32x4){0.f, 0.f, 0.f, 0.f};

    for (int k0 = 0; k0 < K; k0 += 64) {
#pragma unroll
        for (int g = 0; g < 4; ++g) {
            int r = g * 32 + srow;
            gl2lds16(&A[(size_t)(m0 + r) * K + k0 + schunk], &As[r * 64 + schunk]);
            gl2lds16(&Bt[(size_t)(n0 + r) * K + k0 + schunk], &Bs[r * 64 + schunk]);
        }
        __syncthreads();
#pragma unroll
        for (int ks = 0; ks < 64; ks += 32) {
            bf16x8 a[4], b[4];
#pragma unroll
            for (int i = 0; i < 4; ++i)
                a[i] = *(bf16x8*)&As[(wm + i * 16 + m16) * 64 + ks + quad * 8];
#pragma unroll
            for (int j = 0; j < 4; ++j)
                b[j] = *(bf16x8*)&Bs[(wn + j * 16 + m16) * 64 + ks + quad * 8];
#pragma unroll
            for (int i = 0; i < 4; ++i)
#pragma unroll
                for (int j = 0; j < 4; ++j)
                    acc[i][j] = __builtin_amdgcn_mfma_f32_16x16x32_bf16(
                        a[i], b[j], acc[i][j], 0, 0, 0);
        }
        __syncthreads();
    }

    const bool out_f32 = final_out && !isbf;
#pragma unroll
    for (int i = 0; i < 4; ++i) {
        int grow = m0 + wm + i * 16 + quad * 4;
#pragma unroll
        for (int j = 0; j < 4; ++j) {
            int gcol = n0 + wn + j * 16 + m16;
            float bv = isbf ? bf2f(((const u16*)bias)[gcol])
                            : ((const float*)bias)[gcol];
#pragma unroll
            for (int r = 0; r < 4; ++r) {
                float val = acc[i][j][r] + bv;
                size_t idx = (size_t)(grow + r) * N + gcol;
                if (out_f32) ((float*)C)[idx] = val;
                else         ((u16*)C)[idx]   = f2bf(val);
            }
        }
    }
}

// ---------------------------------------------------------------------------
// Flash attention (causal). Block = (b, h, 128-row q tile), 4 waves.
// Q frags in registers; K/Vt staged async into unpadded LDS; mask only on
// the diagonal tile; exp2-domain softmax. LDS 66 KB -> 2 blocks/CU.
// Vt layout: [(b*H+h)*64 + d][T].
// ---------------------------------------------------------------------------
__global__ __launch_bounds__(256, 2) void attn_flash(
    const u16* __restrict__ Q, const u16* __restrict__ Kb,
    const u16* __restrict__ Vt, u16* __restrict__ O, int T, int C)
{
    __shared__ __align__(16) u16 Ks[128 * 64];
    __shared__ __align__(16) u16 Vts[64 * 128];
    __shared__ __align__(16) u16 Ps[128][136];

    const int tid  = threadIdx.x;
    const int lane = tid & 63, wid = tid >> 6;
    const int m16  = lane & 15, quad = lane >> 4;
    const int qt = (gridDim.x - 1) - blockIdx.x;   // heavy tiles first
    const int h = blockIdx.y, b = blockIdx.z;
    const float qscale = 0.125f * 1.44269504f;     // 1/sqrt(64) * log2(e)
    const float NEG = -3.0e4f;

    const size_t headoff = ((size_t)b * T) * C + h * 64;
    const size_t vthead  = ((size_t)(b * gridDim.y + h) * 64) * T;

    // Q fragments in registers, reused across all st iterations
    bf16x8 aq[2][2];
#pragma unroll
    for (int i = 0; i < 2; ++i)
#pragma unroll
        for (int ks = 0; ks < 2; ++ks)
            aq[i][ks] = *(const bf16x8*)&Q[headoff +
                (size_t)(qt * 128 + wid * 32 + i * 16 + m16) * C +
                ks * 32 + quad * 8];

    float m_run[2][4], l_run[2][4];
    f32x4 o_acc[2][4];
#pragma unroll
    for (int i = 0; i < 2; ++i)
#pragma unroll
        for (int r = 0; r < 4; ++r) { m_run[i][r] = NEG; l_run[i][r] = 0.f; }
#pragma unroll
    for (int i = 0; i < 2; ++i)
#pragma unroll
        for (int n = 0; n < 4; ++n) o_acc[i][n] = (f32x4){0.f, 0.f, 0.f, 0.f};

    for (int st = 0; st <= qt; ++st) {
        __syncthreads();   // previous tile fully consumed
        // K tile: 128 rows x 64 elems, async
#pragma unroll
        for (int g = 0; g < 4; ++g) {
            int r = g * 32 + wid * 8 + (lane >> 3);
            gl2lds16(&Kb[headoff + (size_t)(st * 128 + r) * C + (lane & 7) * 8],
                     &Ks[r * 64 + (lane & 7) * 8]);
        }
        // Vt tile: 64 rows x 128 elems, async
#pragma unroll
        for (int g = 0; g < 4; ++g) {
            int r = g * 16 + wid * 4 + (lane >> 4);
            gl2lds16(&Vt[vthead + (size_t)r * T + st * 128 + (lane & 15) * 8],
                     &Vts[r * 128 + (lane & 15) * 8]);
        }
        __syncthreads();

        // S = Q K^T (32 q rows per wave x 128 s cols)
        f32x4 sacc[2][8];
#pragma unroll
        for (int i = 0; i < 2; ++i)
#pragma unroll
            for (int j = 0; j < 8; ++j) sacc[i][j] = (f32x4){0.f, 0.f, 0.f, 0.f};
#pragma unroll
        for (int ks = 0; ks < 2; ++ks) {
            bf16x8 bk[8];
#pragma unroll
            for (int j = 0; j < 8; ++j)
                bk[j] = *(bf16x8*)&Ks[(j * 16 + m16) * 64 + ks * 32 + quad * 8];
#pragma unroll
            for (int i = 0; i < 2; ++i)
#pragma unroll
                for (int j = 0; j < 8; ++j)
                    sacc[i][j] = __builtin_amdgcn_mfma_f32_16x16x32_bf16(
                        aq[i][ks], bk[j], sacc[i][j], 0, 0, 0);
        }

        const bool diag = (st == qt);
#pragma unroll
        for (int i = 0; i < 2; ++i) {
            int qrow = wid * 32 + i * 16 + quad * 4;   // within-tile q row
            float pm[4];
#pragma unroll
            for (int r = 0; r < 4; ++r) pm[r] = NEG;
#pragma unroll
            for (int j = 0; j < 8; ++j) {
                int sg = j * 16 + m16;
#pragma unroll
                for (int r = 0; r < 4; ++r) {
                    float v = sacc[i][j][r] * qscale;   // log2 domain
                    if (diag && sg > qrow + r) v = NEG;
                    sacc[i][j][r] = v;
                    pm[r] = fmaxf(pm[r], v);
                }
            }
#pragma unroll
            for (int off = 1; off < 16; off <<= 1)
#pragma unroll
                for (int r = 0; r < 4; ++r)
                    pm[r] = fmaxf(pm[r], __shfl_xor(pm[r], off));

            float alpha[4], mn[4], rs[4];
#pragma unroll
            for (int r = 0; r < 4; ++r) {
                mn[r] = fmaxf(m_run[i][r], pm[r]);
                alpha[r] = exp2f(m_run[i][r] - mn[r]);
                m_run[i][r] = mn[r];
                rs[r] = 0.f;
            }
#pragma unroll
            for (int j = 0; j < 8; ++j) {
#pragma unroll
                for (int r = 0; r < 4; ++r) {
                    float p = exp2f(sacc[i][j][r] - mn[r]);
                    rs[r] += p;
                    unsigned u = __float_as_uint(p);
                    Ps[wid * 32 + i * 16 + quad * 4 + r][j * 16 + m16] =
                        (u16)((u + 0x8000u) >> 16);
                }
            }
#pragma unroll
            for (int off = 1; off < 16; off <<= 1)
#pragma unroll
                for (int r = 0; r < 4; ++r) rs[r] += __shfl_xor(rs[r], off);
#pragma unroll
            for (int r = 0; r < 4; ++r)
                l_run[i][r] = l_run[i][r] * alpha[r] + rs[r];
#pragma unroll
            for (int n = 0; n < 4; ++n)
#pragma unroll
                for (int r = 0; r < 4; ++r) o_acc[i][n][r] *= alpha[r];
        }
        __syncthreads();   // Ps complete before PV reads

        // O += P V
#pragma unroll
        for (int k4 = 0; k4 < 4; ++k4) {
            bf16x8 ap[2], bv[4];
#pragma unroll
            for (int i = 0; i < 2; ++i)
                ap[i] = *(bf16x8*)&Ps[wid * 32 + i * 16 + m16][k4 * 32 + quad * 8];
#pragma unroll
            for (int n = 0; n < 4; ++n)
                bv[n] = *(bf16x8*)&Vts[(n * 16 + m16) * 128 + k4 * 32 + quad * 8];
#pragma unroll
            for (int i = 0; i < 2; ++i)
#pragma unroll
                for (int n = 0; n < 4; ++n)
                    o_acc[i][n] = __builtin_amdgcn_mfma_f32_16x16x32_bf16(
                        ap[i], bv[n], o_acc[i][n], 0, 0, 0);
        }
    }

#pragma unroll
    for (int i = 0; i < 2; ++i) {
#pragma unroll
        for (int n = 0; n < 4; ++n) {
#pragma unroll
            for (int r = 0; r < 4; ++r) {
                int tq = qt * 128 + wid * 32 + i * 16 + quad * 4 + r;
                O[((size_t)b * T + tq) * C + h * 64 + n * 16 + m16] =
                    f2bf(o_acc[i][n][r] / l_run[i][r]);
            }
        }
    }
}

// ---------------------------------------------------------------------------
extern "C" void kernel_launch(void* const* d_in, const int* in_sizes, int n_in,
                              void* d_out, int out_size, void* d_ws, size_t ws_size,
                              hipStream_t stream)
{
    const void* x  = d_in[0];
    const void* Wq = d_in[1];
    const void* bq = d_in[2];
    const void* Wk = d_in[3];
    const void* bk = d_in[4];
    const void* Wv = d_in[5];
    const void* bv = d_in[6];
    const void* Wp = d_in[7];
    const void* bp = d_in[8];

    const int Bb = 4, T = 2048, C = 1024, H = 16;
    const int M = Bb * T, N = C, K = C;

    u16* wsp = (u16*)d_ws;
    const size_t WSZ = (size_t)C * C;   // 1 Mi elems
    const size_t MSZ = (size_t)M * C;   // 8 Mi elems
    u16* WtQ  = wsp;
    u16* WtK  = wsp + WSZ;
    u16* WtV  = wsp + 2 * WSZ;
    u16* WtP  = wsp + 3 * WSZ;
    u16* xb   = wsp + 4 * WSZ;
    u16* Qb   = xb + MSZ;
    u16* Kbf  = Qb + MSZ;
    u16* Vslot = Kbf + MSZ;   // holds V^T after transpose
    u16* tmp   = Vslot + MSZ; // holds V (GEMM out), then attention out
    int* flag  = (int*)(tmp + MSZ);

    detect_dtype<<<1, 128, 0, stream>>>((const u16*)x, flag);
    convert_in<<<(int)(MSZ / 4 / 256), 256, 0, stream>>>(x, xb, MSZ / 4, flag);

    dim3 tb(256), tg(C / 32, C / 32);
    transpose_conv<<<tg, tb, 0, stream>>>(Wq, WtQ, C, C, flag);
    transpose_conv<<<tg, tb, 0, stream>>>(Wk, WtK, C, C, flag);
    transpose_conv<<<tg, tb, 0, stream>>>(Wv, WtV, C, C, flag);
    transpose_conv<<<tg, tb, 0, stream>>>(Wp, WtP, C, C, flag);

    dim3 gg(N / 128, M / 128), gb(256);
    gemm_bias<<<gg, gb, 0, stream>>>(xb, WtQ, bq, Qb,   M, N, K, 0, flag);
    gemm_bias<<<gg, gb, 0, stream>>>(xb, WtK, bk, Kbf,  M, N, K, 0, flag);
    gemm_bias<<<gg, gb, 0, stream>>>(xb, WtV, bv, tmp,  M, N, K, 0, flag);

    dim3 vg(T / 32, 2, Bb * H), vb(256);
    transpose_v<<<vg, vb, 0, stream>>>(tmp, Vslot, T, C);

    dim3 ag(T / 128, H, Bb), ab(256);
    attn_flash<<<ag, ab, 0, stream>>>(Qb, Kbf, Vslot, tmp, T, C);

    gemm_bias<<<gg, gb, 0, stream>>>(tmp, WtP, bp, d_out, M, N, K, 1, flag);
}

// Round 4
// 470.370 us; speedup vs baseline: 1.1457x; 1.1345x over previous
//
#include <hip/hip_runtime.h>

typedef unsigned short u16;
typedef __attribute__((ext_vector_type(8))) short bf16x8;
typedef __attribute__((ext_vector_type(4))) float f32x4;

__device__ __forceinline__ float bf2f(u16 h) {
    return __uint_as_float(((unsigned int)h) << 16);
}
__device__ __forceinline__ u16 f2bf(float f) {
    unsigned int u = __float_as_uint(f);
    u += 0x7FFFu + ((u >> 16) & 1u);   // RNE
    return (u16)(u >> 16);
}

// async global->LDS, 16 B per lane. LDS dest = wave-uniform base + lane*16.
__device__ __forceinline__ void gl2lds16(const u16* g, u16* l) {
    __builtin_amdgcn_global_load_lds(
        (const __attribute__((address_space(1))) unsigned int*)g,
        (__attribute__((address_space(3))) unsigned int*)l,
        16, 0, 0);
}

// ---------------------------------------------------------------------------
// Dtype detection (fp32 vs bf16 input buffers). flag=1 -> bf16.
// ---------------------------------------------------------------------------
__global__ void detect_dtype(const u16* __restrict__ x, int* __restrict__ flag) {
    __shared__ int cnt;
    if (threadIdx.x == 0) cnt = 0;
    __syncthreads();
    unsigned e = (x[2 * threadIdx.x] >> 7) & 0xFF;
    if (e >= 116 && e <= 132) atomicAdd(&cnt, 1);
    __syncthreads();
    if (threadIdx.x == 0) *flag = (cnt >= 96) ? 1 : 0;
}

// ---------------------------------------------------------------------------
// Elementwise convert to bf16 (or bit-copy). n4 = n/4.
// ---------------------------------------------------------------------------
__global__ __launch_bounds__(256) void convert_in(
    const void* __restrict__ in, u16* __restrict__ out, long n4,
    const int* __restrict__ flag)
{
    long i = (long)blockIdx.x * blockDim.x + threadIdx.x;
    if (i >= n4) return;
    if (*flag) {
        ((ushort4*)out)[i] = ((const ushort4*)in)[i];
    } else {
        float4 v = ((const float4*)in)[i];
        ushort4 r;
        r.x = f2bf(v.x); r.y = f2bf(v.y); r.z = f2bf(v.z); r.w = f2bf(v.w);
        ((ushort4*)out)[i] = r;
    }
}

// ---------------------------------------------------------------------------
// Transpose [R x Cc] -> [Cc x R] with dtype convert fused (weights).
// ---------------------------------------------------------------------------
__global__ __launch_bounds__(256) void transpose_conv(
    const void* __restrict__ in, u16* __restrict__ out, int R, int Cc,
    const int* __restrict__ flag)
{
    __shared__ u16 tile[32][33];
    int tx = threadIdx.x & 31, ty = threadIdx.x >> 5;
    int c0 = blockIdx.x * 32, r0 = blockIdx.y * 32;
    bool isbf = (*flag != 0);
#pragma unroll
    for (int g = 0; g < 4; ++g) {
        size_t idx = (size_t)(r0 + ty + g * 8) * Cc + c0 + tx;
        tile[ty + g * 8][tx] = isbf ? ((const u16*)in)[idx]
                                    : f2bf(((const float*)in)[idx]);
    }
    __syncthreads();
#pragma unroll
    for (int g = 0; g < 4; ++g)
        out[(size_t)(c0 + ty + g * 8) * R + r0 + tx] = tile[tx][ty + g * 8];
}

// ---------------------------------------------------------------------------
// V[b][s][h*64+d] -> Vt[(b*H+h)*64+d][s]   (bf16). Grid: (T/32, 2, B*H).
// ---------------------------------------------------------------------------
__global__ __launch_bounds__(256) void transpose_v(
    const u16* __restrict__ V, u16* __restrict__ Vt, int T, int C)
{
    __shared__ u16 tile[32][33];
    int tx = threadIdx.x & 31, ty = threadIdx.x >> 5;
    int s0 = blockIdx.x * 32, d0 = blockIdx.y * 32;
    int bh = blockIdx.z;              // b*16+h
    int b = bh >> 4, h = bh & 15;
#pragma unroll
    for (int g = 0; g < 4; ++g)
        tile[ty + g * 8][tx] =
            V[((size_t)b * T + s0 + ty + g * 8) * C + h * 64 + d0 + tx];
    __syncthreads();
#pragma unroll
    for (int g = 0; g < 4; ++g)
        Vt[((size_t)bh * 64 + d0 + ty + g * 8) * T + s0 + tx] =
            tile[tx][ty + g * 8];
}

// ---------------------------------------------------------------------------
// C[M,N] = A[M,K] @ W + bias, Bt = W^T [N,K] bf16. m97-style staging.
// ---------------------------------------------------------------------------
__global__ __launch_bounds__(256, 2) void gemm_bias(
    const u16* __restrict__ A, const u16* __restrict__ Bt,
    const void* __restrict__ bias, void* __restrict__ C,
    int M, int N, int K, int final_out, const int* __restrict__ flag)
{
    __shared__ __align__(16) u16 As[128 * 64];
    __shared__ __align__(16) u16 Bs[128 * 64];

    const int tid  = threadIdx.x;
    const int m0   = blockIdx.y * 128, n0 = blockIdx.x * 128;
    const int lane = tid & 63, wid = tid >> 6;
    const int wm   = (wid >> 1) * 64, wn = (wid & 1) * 64;
    const int m16  = lane & 15, quad = lane >> 4;
    const int isbf = *flag;

    const int srow   = wid * 8 + (lane >> 3);
    const int schunk = (lane & 7) * 8;

    f32x4 acc[4][4];
#pragma unroll
    for (int i = 0; i < 4; ++i)
#pragma unroll
        for (int j = 0; j < 4; ++j)
            acc[i][j] = (f32x4){0.f, 0.f, 0.f, 0.f};

    for (int k0 = 0; k0 < K; k0 += 64) {
#pragma unroll
        for (int g = 0; g < 4; ++g) {
            int r = g * 32 + srow;
            gl2lds16(&A[(size_t)(m0 + r) * K + k0 + schunk], &As[r * 64 + schunk]);
            gl2lds16(&Bt[(size_t)(n0 + r) * K + k0 + schunk], &Bs[r * 64 + schunk]);
        }
        __syncthreads();
#pragma unroll
        for (int ks = 0; ks < 64; ks += 32) {
            bf16x8 a[4], b[4];
#pragma unroll
            for (int i = 0; i < 4; ++i)
                a[i] = *(bf16x8*)&As[(wm + i * 16 + m16) * 64 + ks + quad * 8];
#pragma unroll
            for (int j = 0; j < 4; ++j)
                b[j] = *(bf16x8*)&Bs[(wn + j * 16 + m16) * 64 + ks + quad * 8];
#pragma unroll
            for (int i = 0; i < 4; ++i)
#pragma unroll
                for (int j = 0; j < 4; ++j)
                    acc[i][j] = __builtin_amdgcn_mfma_f32_16x16x32_bf16(
                        a[i], b[j], acc[i][j], 0, 0, 0);
        }
        __syncthreads();
    }

    const bool out_f32 = final_out && !isbf;
#pragma unroll
    for (int i = 0; i < 4; ++i) {
        int grow = m0 + wm + i * 16 + quad * 4;
#pragma unroll
        for (int j = 0; j < 4; ++j) {
            int gcol = n0 + wn + j * 16 + m16;
            float bv = isbf ? bf2f(((const u16*)bias)[gcol])
                            : ((const float*)bias)[gcol];
#pragma unroll
            for (int r = 0; r < 4; ++r) {
                float val = acc[i][j][r] + bv;
                size_t idx = (size_t)(grow + r) * N + gcol;
                if (out_f32) ((float*)C)[idx] = val;
                else         ((u16*)C)[idx]   = f2bf(val);
            }
        }
    }
}

// ---------------------------------------------------------------------------
// Flash attention (causal), S^T orientation.
// Block = (b, h, 128 q rows), 4 waves x 32 q rows.
// S^T = K·Q^T: lane's q = m16 -> scalar softmax state, 2-shuffle reductions.
// Ks/Vts/Ps XOR-swizzled at 16B granularity -> conflict-free frag reads.
// Ps is per-wave private (rows wid*32..+31): no barrier before PV.
// ---------------------------------------------------------------------------
__global__ __launch_bounds__(256, 2) void attn_flash(
    const u16* __restrict__ Q, const u16* __restrict__ Kb,
    const u16* __restrict__ Vt, u16* __restrict__ O, int T, int C)
{
    __shared__ __align__(16) u16 Ks[128 * 64];    // [s][d], swizzled
    __shared__ __align__(16) u16 Vts[64 * 128];   // [d][s], swizzled
    __shared__ __align__(16) u16 Ps[128 * 128];   // [q][s], swizzled

    const int tid  = threadIdx.x;
    const int lane = tid & 63, wid = tid >> 6;
    const int m16  = lane & 15, quad = lane >> 4;
    const int sw   = m16 & 7;                      // XOR swizzle key
    const int qt = (gridDim.x - 1) - blockIdx.x;   // heavy tiles first
    const int h = blockIdx.y, b = blockIdx.z;
    const float qscale = 0.125f * 1.44269504f;     // 1/sqrt(64) * log2(e)
    const float NEG = -3.0e4f;

    const size_t headoff = ((size_t)b * T) * C + h * 64;
    const size_t vthead  = ((size_t)(b * gridDim.y + h) * 64) * T;

    // Q B-fragments in registers (B: k=d=quad*8+jj, n=q=m16)
    bf16x8 aq[2][2];
#pragma unroll
    for (int i = 0; i < 2; ++i)
#pragma unroll
        for (int ks = 0; ks < 2; ++ks)
            aq[i][ks] = *(const bf16x8*)&Q[headoff +
                (size_t)(qt * 128 + wid * 32 + i * 16 + m16) * C +
                ks * 32 + quad * 8];

    float m_run[2], l_run[2];
    f32x4 o_acc[2][4];
#pragma unroll
    for (int i = 0; i < 2; ++i) { m_run[i] = NEG; l_run[i] = 0.f; }
#pragma unroll
    for (int i = 0; i < 2; ++i)
#pragma unroll
        for (int n = 0; n < 4; ++n) o_acc[i][n] = (f32x4){0.f, 0.f, 0.f, 0.f};

    for (int st = 0; st <= qt; ++st) {
        __syncthreads();   // previous tile fully consumed
        // K tile [128][64]: swizzled source chunk, dest = base + lane*16
#pragma unroll
        for (int g = 0; g < 4; ++g) {
            int r  = g * 32 + wid * 8 + (lane >> 3);
            int cg = (lane & 7) ^ (r & 7);
            gl2lds16(&Kb[headoff + (size_t)(st * 128 + r) * C + cg * 8],
                     &Ks[r * 64 + (lane & 7) * 8]);
        }
        // Vt tile [64][128]
#pragma unroll
        for (int g = 0; g < 4; ++g) {
            int r  = g * 16 + wid * 4 + (lane >> 4);
            int cg = (lane & 15) ^ (r & 7);
            gl2lds16(&Vt[vthead + (size_t)r * T + st * 128 + cg * 8],
                     &Vts[r * 128 + (lane & 15) * 8]);
        }
        __syncthreads();

        // S^T = K Q^T : lane holds q = i*16+m16 (col), s = j*16+quad*4+r (row)
        f32x4 sacc[2][8];
#pragma unroll
        for (int i = 0; i < 2; ++i)
#pragma unroll
            for (int j = 0; j < 8; ++j) sacc[i][j] = (f32x4){0.f, 0.f, 0.f, 0.f};
#pragma unroll
        for (int ks = 0; ks < 2; ++ks) {
            bf16x8 bk[8];
#pragma unroll
            for (int j = 0; j < 8; ++j)
                bk[j] = *(bf16x8*)&Ks[(j * 16 + m16) * 64 +
                                      (((ks * 4 + quad) ^ sw) * 8)];
#pragma unroll
            for (int i = 0; i < 2; ++i)
#pragma unroll
                for (int j = 0; j < 8; ++j)
                    sacc[i][j] = __builtin_amdgcn_mfma_f32_16x16x32_bf16(
                        bk[j], aq[i][ks], sacc[i][j], 0, 0, 0);
        }

        const bool diag = (st == qt);
#pragma unroll
        for (int i = 0; i < 2; ++i) {
            const int q_in = wid * 32 + i * 16 + m16;
            // mask (diag only) + in-lane max over 32 raw scores
            float pm = NEG;
#pragma unroll
            for (int j = 0; j < 8; ++j) {
#pragma unroll
                for (int r = 0; r < 4; ++r) {
                    float v = sacc[i][j][r];
                    if (diag && (j * 16 + quad * 4 + r) > q_in) v = -3.0e5f;
                    sacc[i][j][r] = v;
                    pm = fmaxf(pm, v);
                }
            }
            pm = fmaxf(pm, __shfl_xor(pm, 16));
            pm = fmaxf(pm, __shfl_xor(pm, 32));
            float mn = fmaxf(m_run[i], pm * qscale);
            float alpha = exp2f(m_run[i] - mn);
            m_run[i] = mn;
            float rs = 0.f;
#pragma unroll
            for (int j = 0; j < 8; ++j) {
                float p0 = exp2f(fmaf(sacc[i][j][0], qscale, -mn));
                float p1 = exp2f(fmaf(sacc[i][j][1], qscale, -mn));
                float p2 = exp2f(fmaf(sacc[i][j][2], qscale, -mn));
                float p3 = exp2f(fmaf(sacc[i][j][3], qscale, -mn));
                rs += (p0 + p1) + (p2 + p3);
                unsigned lo = ((__float_as_uint(p0) + 0x8000u) >> 16) |
                              ((__float_as_uint(p1) + 0x8000u) & 0xFFFF0000u);
                unsigned hi = ((__float_as_uint(p2) + 0x8000u) >> 16) |
                              ((__float_as_uint(p3) + 0x8000u) & 0xFFFF0000u);
                // write 4 probs (s = j*16+quad*4..+3) for q row; 16B chunk
                // index = j*2 + (quad>>1), swizzled by sw, half = quad&1
                *(uint2*)&Ps[(wid * 32 + i * 16 + m16) * 128 +
                             (((j * 2 + (quad >> 1)) ^ sw) * 8) +
                             (quad & 1) * 4] = make_uint2(lo, hi);
            }
            rs += __shfl_xor(rs, 16);
            rs += __shfl_xor(rs, 32);
            l_run[i] = l_run[i] * alpha + rs;
            // rescale O (its q = i*16 + quad*4 + r): gather alpha per r
            float ar[4];
#pragma unroll
            for (int r = 0; r < 4; ++r) ar[r] = __shfl(alpha, quad * 4 + r);
#pragma unroll
            for (int n = 0; n < 4; ++n)
#pragma unroll
                for (int r = 0; r < 4; ++r) o_acc[i][n][r] *= ar[r];
        }
        // Ps is same-wave private: lgkmcnt ordering only, no barrier.

        // O += P V  (A: m=q=m16, k=s=quad*8+jj ; B: k=s, n=d=m16)
#pragma unroll
        for (int k4 = 0; k4 < 4; ++k4) {
            bf16x8 ap[2], bv[4];
#pragma unroll
            for (int i = 0; i < 2; ++i)
                ap[i] = *(bf16x8*)&Ps[(wid * 32 + i * 16 + m16) * 128 +
                                      (((k4 * 4 + quad) ^ sw) * 8)];
#pragma unroll
            for (int n = 0; n < 4; ++n)
                bv[n] = *(bf16x8*)&Vts[(n * 16 + m16) * 128 +
                                       (((k4 * 4 + quad) ^ sw) * 8)];
#pragma unroll
            for (int i = 0; i < 2; ++i)
#pragma unroll
                for (int n = 0; n < 4; ++n)
                    o_acc[i][n] = __builtin_amdgcn_mfma_f32_16x16x32_bf16(
                        ap[i], bv[n], o_acc[i][n], 0, 0, 0);
        }
    }

    // epilogue: gather l into O layout, normalize, store
#pragma unroll
    for (int i = 0; i < 2; ++i) {
        float linv[4];
#pragma unroll
        for (int r = 0; r < 4; ++r)
            linv[r] = 1.f / __shfl(l_run[i], quad * 4 + r);
#pragma unroll
        for (int n = 0; n < 4; ++n) {
#pragma unroll
            for (int r = 0; r < 4; ++r) {
                int tq = qt * 128 + wid * 32 + i * 16 + quad * 4 + r;
                O[((size_t)b * T + tq) * C + h * 64 + n * 16 + m16] =
                    f2bf(o_acc[i][n][r] * linv[r]);
            }
        }
    }
}

// ---------------------------------------------------------------------------
extern "C" void kernel_launch(void* const* d_in, const int* in_sizes, int n_in,
                              void* d_out, int out_size, void* d_ws, size_t ws_size,
                              hipStream_t stream)
{
    const void* x  = d_in[0];
    const void* Wq = d_in[1];
    const void* bq = d_in[2];
    const void* Wk = d_in[3];
    const void* bk = d_in[4];
    const void* Wv = d_in[5];
    const void* bv = d_in[6];
    const void* Wp = d_in[7];
    const void* bp = d_in[8];

    const int Bb = 4, T = 2048, C = 1024, H = 16;
    const int M = Bb * T, N = C, K = C;

    u16* wsp = (u16*)d_ws;
    const size_t WSZ = (size_t)C * C;
    const size_t MSZ = (size_t)M * C;
    u16* WtQ  = wsp;
    u16* WtK  = wsp + WSZ;
    u16* WtV  = wsp + 2 * WSZ;
    u16* WtP  = wsp + 3 * WSZ;
    u16* xb   = wsp + 4 * WSZ;
    u16* Qb   = xb + MSZ;
    u16* Kbf  = Qb + MSZ;
    u16* Vslot = Kbf + MSZ;   // V^T after transpose
    u16* tmp   = Vslot + MSZ; // V (GEMM out), then attention out
    int* flag  = (int*)(tmp + MSZ);

    detect_dtype<<<1, 128, 0, stream>>>((const u16*)x, flag);
    convert_in<<<(int)(MSZ / 4 / 256), 256, 0, stream>>>(x, xb, MSZ / 4, flag);

    dim3 tb(256), tg(C / 32, C / 32);
    transpose_conv<<<tg, tb, 0, stream>>>(Wq, WtQ, C, C, flag);
    transpose_conv<<<tg, tb, 0, stream>>>(Wk, WtK, C, C, flag);
    transpose_conv<<<tg, tb, 0, stream>>>(Wv, WtV, C, C, flag);
    transpose_conv<<<tg, tb, 0, stream>>>(Wp, WtP, C, C, flag);

    dim3 gg(N / 128, M / 128), gb(256);
    gemm_bias<<<gg, gb, 0, stream>>>(xb, WtQ, bq, Qb,   M, N, K, 0, flag);
    gemm_bias<<<gg, gb, 0, stream>>>(xb, WtK, bk, Kbf,  M, N, K, 0, flag);
    gemm_bias<<<gg, gb, 0, stream>>>(xb, WtV, bv, tmp,  M, N, K, 0, flag);

    dim3 vg(T / 32, 2, Bb * H), vb(256);
    transpose_v<<<vg, vb, 0, stream>>>(tmp, Vslot, T, C);

    dim3 ag(T / 128, H, Bb), ab(256);
    attn_flash<<<ag, ab, 0, stream>>>(Qb, Kbf, Vslot, tmp, T, C);

    gemm_bias<<<gg, gb, 0, stream>>>(tmp, WtP, bp, d_out, M, N, K, 1, flag);
}